// Round 1
// baseline (235.904 us; speedup 1.0000x reference)
//
#include <hip/hip_runtime.h>
#include <hip/hip_bf16.h>
#include <math.h>

#define N_NODES 50000
#define N_EDGES 800000
#define IN_DIM 128
#define OUT_DIM 64

// ---------------------------------------------------------------------------
// K1: h = x @ W  (fp32, vector ALU — no fp32 MFMA on CDNA4)
//     also a1[n] = h[n]·att[0:64], a2[n] = h[n]·att[64:128]
// block 256 = 4 waves; each wave computes 8 rows (lane = output col).
// W (128x64 = 32KB) staged in LDS; x rows read via wave-uniform addresses
// (readfirstlane'd base) so the compiler can emit scalar loads.
// ---------------------------------------------------------------------------
__global__ __launch_bounds__(256) void k1_gemm(
    const float* __restrict__ x, const float* __restrict__ W,
    const float* __restrict__ att,
    float* __restrict__ h, float* __restrict__ a1, float* __restrict__ a2) {
  __shared__ float Wl[IN_DIM * OUT_DIM];  // 32 KB
  int tid = threadIdx.x;
  for (int i = tid; i < IN_DIM * OUT_DIM / 4; i += 256) {
    ((float4*)Wl)[i] = ((const float4*)W)[i];
  }
  __syncthreads();

  int wid = tid >> 6, lane = tid & 63;
  int row0 = (blockIdx.x * 4 + wid) * 8;
  row0 = __builtin_amdgcn_readfirstlane(row0);

  const float* xpr[8];
#pragma unroll
  for (int r = 0; r < 8; ++r) {
    int rr = row0 + r;
    if (rr >= N_NODES) rr = N_NODES - 1;  // clamp loads; stores guarded below
    xpr[r] = x + (size_t)rr * IN_DIM;
  }

  float acc[8] = {0.f, 0.f, 0.f, 0.f, 0.f, 0.f, 0.f, 0.f};
  for (int k = 0; k < IN_DIM; k += 4) {
    float w0 = Wl[(k + 0) * OUT_DIM + lane];
    float w1 = Wl[(k + 1) * OUT_DIM + lane];
    float w2 = Wl[(k + 2) * OUT_DIM + lane];
    float w3 = Wl[(k + 3) * OUT_DIM + lane];
#pragma unroll
    for (int r = 0; r < 8; ++r) {
      float4 xv = *(const float4*)(xpr[r] + k);  // wave-uniform -> s_load
      acc[r] = fmaf(xv.x, w0, acc[r]);
      acc[r] = fmaf(xv.y, w1, acc[r]);
      acc[r] = fmaf(xv.z, w2, acc[r]);
      acc[r] = fmaf(xv.w, w3, acc[r]);
    }
  }

  float t1 = att[lane], t2 = att[OUT_DIM + lane];
#pragma unroll
  for (int r = 0; r < 8; ++r) {
    int row = row0 + r;
    if (row >= N_NODES) break;
    float v = acc[r];
    h[(size_t)row * OUT_DIM + lane] = v;
    float p1 = v * t1, p2 = v * t2;
#pragma unroll
    for (int o = 32; o >= 1; o >>= 1) {
      p1 += __shfl_xor(p1, o, 64);
      p2 += __shfl_xor(p2, o, 64);
    }
    if (lane == 0) { a1[row] = p1; a2[row] = p2; }
  }
}

// ---------------------------------------------------------------------------
// K2: histogram of edge destinations
// ---------------------------------------------------------------------------
__global__ __launch_bounds__(256) void k2_hist(const int* __restrict__ dstp,
                                               int* __restrict__ deg) {
  int i = blockIdx.x * 256 + threadIdx.x;
  if (i < N_EDGES) atomicAdd(&deg[dstp[i]], 1);
}

// ---------------------------------------------------------------------------
// K3: single-block exclusive scan of deg -> off (and cursor copy -> pos)
// 1024 threads, 8 items/thread, wave-shfl scan + 16-wave LDS combine.
// ---------------------------------------------------------------------------
__global__ __launch_bounds__(1024) void k3_scan(const int* __restrict__ deg,
                                                int* __restrict__ off,
                                                int* __restrict__ pos) {
  __shared__ int swave[16];
  __shared__ int scarry;
  int tid = threadIdx.x;
  int lane = tid & 63, wid = tid >> 6;
  if (tid == 0) scarry = 0;
  __syncthreads();

  const int TILE = 1024 * 8;
  for (int base = 0; base < N_NODES; base += TILE) {
    int v[8];
    int idx0 = base + tid * 8;
    int local = 0;
#pragma unroll
    for (int j = 0; j < 8; ++j) {
      int i = idx0 + j;
      v[j] = (i < N_NODES) ? deg[i] : 0;
      local += v[j];
    }
    // wave-inclusive scan of per-thread sums
    int incl = local;
#pragma unroll
    for (int o = 1; o < 64; o <<= 1) {
      int t = __shfl_up(incl, o, 64);
      if (lane >= o) incl += t;
    }
    if (lane == 63) swave[wid] = incl;
    __syncthreads();
    if (wid == 0) {
      int wv = (lane < 16) ? swave[lane] : 0;
      int wi = wv;
#pragma unroll
      for (int o = 1; o < 16; o <<= 1) {
        int t = __shfl_up(wi, o, 64);
        if (lane >= o) wi += t;
      }
      if (lane < 16) swave[lane] = wi - wv;  // exclusive wave prefix
    }
    __syncthreads();
    int excl = incl - local + swave[wid] + scarry;
#pragma unroll
    for (int j = 0; j < 8; ++j) {
      int i = idx0 + j;
      if (i < N_NODES) { off[i] = excl; pos[i] = excl; }
      excl += v[j];
    }
    __syncthreads();
    if (tid == 1023) scarry = excl;  // = old carry + tile total
    __syncthreads();
  }
  if (tid == 0) off[N_NODES] = scarry;  // == N_EDGES
}

// ---------------------------------------------------------------------------
// K4: per-edge logit + scatter into dst-sorted order via atomic cursors
// ---------------------------------------------------------------------------
__global__ __launch_bounds__(256) void k4_scatter(
    const int* __restrict__ src, const int* __restrict__ dstp,
    const float* __restrict__ a1, const float* __restrict__ a2,
    int* __restrict__ pos, int* __restrict__ ssrc, float* __restrict__ se) {
  int i = blockIdx.x * 256 + threadIdx.x;
  if (i >= N_EDGES) return;
  int s = src[i], d = dstp[i];
  float ev = a1[s] + a2[d];
  ev = ev > 0.f ? ev : 0.2f * ev;  // leaky_relu, slope 0.2
  int p = atomicAdd(&pos[d], 1);
  ssrc[p] = s;
  se[p] = ev;
}

// ---------------------------------------------------------------------------
// K5: per-node softmax + weighted aggregation + ELU. One wave per node.
// ---------------------------------------------------------------------------
__global__ __launch_bounds__(256) void k5_agg(
    const int* __restrict__ off, const int* __restrict__ ssrc,
    const float* __restrict__ se, const float* __restrict__ h,
    float* __restrict__ out) {
  int wid = threadIdx.x >> 6, lane = threadIdx.x & 63;
  int n = blockIdx.x * 4 + wid;
  if (n >= N_NODES) return;
  int b = off[n], e = off[n + 1];

  float m = -1e30f;
  for (int j = b + lane; j < e; j += 64) m = fmaxf(m, se[j]);
#pragma unroll
  for (int o = 32; o >= 1; o >>= 1) m = fmaxf(m, __shfl_xor(m, o, 64));

  float sum = 0.f;
  for (int j = b + lane; j < e; j += 64) sum += __expf(se[j] - m);
#pragma unroll
  for (int o = 32; o >= 1; o >>= 1) sum += __shfl_xor(sum, o, 64);

  float acc = 0.f;
  for (int j = b; j < e; ++j) {
    int s = ssrc[j];                    // wave-uniform
    float w = __expf(se[j] - m);        // wave-uniform
    acc += w * h[(size_t)s * OUT_DIM + lane];  // coalesced 256B row
  }
  acc = (e > b) ? (acc / sum) : 0.f;
  out[(size_t)n * OUT_DIM + lane] = acc > 0.f ? acc : (__expf(acc) - 1.f);
}

// ---------------------------------------------------------------------------
extern "C" void kernel_launch(void* const* d_in, const int* in_sizes, int n_in,
                              void* d_out, int out_size, void* d_ws, size_t ws_size,
                              hipStream_t stream) {
  const float* x   = (const float*)d_in[0];
  const int*   ei  = (const int*)d_in[1];   // [2, E] int32
  const float* W   = (const float*)d_in[2];
  const float* att = (const float*)d_in[3];
  float* out = (float*)d_out;

  // workspace layout (all 4B elems): ~20.2 MB total
  float* h  = (float*)d_ws;                       // N*64
  float* a1 = h + (size_t)N_NODES * OUT_DIM;      // N
  float* a2 = a1 + N_NODES;                       // N
  int* deg  = (int*)(a2 + N_NODES);               // N
  int* off  = deg + N_NODES;                      // N+1
  int* pos  = off + (N_NODES + 1);                // N
  int* ssrc = pos + N_NODES;                      // E
  float* se = (float*)(ssrc + N_EDGES);           // E

  const int* src  = ei;
  const int* dstp = ei + N_EDGES;

  hipMemsetAsync(deg, 0, N_NODES * sizeof(int), stream);
  k1_gemm<<<(N_NODES + 31) / 32, 256, 0, stream>>>(x, W, att, h, a1, a2);
  k2_hist<<<(N_EDGES + 255) / 256, 256, 0, stream>>>(dstp, deg);
  k3_scan<<<1, 1024, 0, stream>>>(deg, off, pos);
  k4_scatter<<<(N_EDGES + 255) / 256, 256, 0, stream>>>(src, dstp, a1, a2, pos, ssrc, se);
  k5_agg<<<(N_NODES + 3) / 4, 256, 0, stream>>>(off, ssrc, se, h, out);
}

// Round 2
// 170.897 us; speedup vs baseline: 1.3804x; 1.3804x over previous
//
#include <hip/hip_runtime.h>
#include <hip/hip_bf16.h>
#include <hip/hip_fp16.h>
#include <math.h>

#define N_NODES 50000
#define N_EDGES 800000
#define IN_DIM 128
#define OUT_DIM 64

// ---------------------------------------------------------------------------
// K1: h = x @ W (fp32 vector ALU; no fp32 MFMA on CDNA4).
//     h stored as fp16 (only consumer is the weighted gather in K5).
//     a1[n] = h[n]-att[0:64], a2[n] = h[n]-att[64:128] (fp32, in-register).
// ---------------------------------------------------------------------------
__global__ __launch_bounds__(256) void k1_gemm(
    const float* __restrict__ x, const float* __restrict__ W,
    const float* __restrict__ att,
    __half* __restrict__ h, float* __restrict__ a1, float* __restrict__ a2) {
  __shared__ float Wl[IN_DIM * OUT_DIM];  // 32 KB
  int tid = threadIdx.x;
  for (int i = tid; i < IN_DIM * OUT_DIM / 4; i += 256) {
    ((float4*)Wl)[i] = ((const float4*)W)[i];
  }
  __syncthreads();

  int wid = tid >> 6, lane = tid & 63;
  int row0 = (blockIdx.x * 4 + wid) * 8;
  row0 = __builtin_amdgcn_readfirstlane(row0);

  const float* xpr[8];
#pragma unroll
  for (int r = 0; r < 8; ++r) {
    int rr = row0 + r;
    if (rr >= N_NODES) rr = N_NODES - 1;  // clamp loads; stores guarded below
    xpr[r] = x + (size_t)rr * IN_DIM;
  }

  float acc[8] = {0.f, 0.f, 0.f, 0.f, 0.f, 0.f, 0.f, 0.f};
  for (int k = 0; k < IN_DIM; k += 4) {
    float w0 = Wl[(k + 0) * OUT_DIM + lane];
    float w1 = Wl[(k + 1) * OUT_DIM + lane];
    float w2 = Wl[(k + 2) * OUT_DIM + lane];
    float w3 = Wl[(k + 3) * OUT_DIM + lane];
#pragma unroll
    for (int r = 0; r < 8; ++r) {
      float4 xv = *(const float4*)(xpr[r] + k);  // wave-uniform address
      acc[r] = fmaf(xv.x, w0, acc[r]);
      acc[r] = fmaf(xv.y, w1, acc[r]);
      acc[r] = fmaf(xv.z, w2, acc[r]);
      acc[r] = fmaf(xv.w, w3, acc[r]);
    }
  }

  float t1 = att[lane], t2 = att[OUT_DIM + lane];
#pragma unroll
  for (int r = 0; r < 8; ++r) {
    int row = row0 + r;
    if (row >= N_NODES) break;
    float v = acc[r];
    h[(size_t)row * OUT_DIM + lane] = __float2half(v);
    float p1 = v * t1, p2 = v * t2;
#pragma unroll
    for (int o = 32; o >= 1; o >>= 1) {
      p1 += __shfl_xor(p1, o, 64);
      p2 += __shfl_xor(p2, o, 64);
    }
    if (lane == 0) { a1[row] = p1; a2[row] = p2; }
  }
}

// ---------------------------------------------------------------------------
// K2: per-edge logit e = leaky_relu(a1[src]+a2[dst]) + dst histogram
// ---------------------------------------------------------------------------
__global__ __launch_bounds__(256) void k2_edge(
    const int* __restrict__ src, const int* __restrict__ dstp,
    const float* __restrict__ a1, const float* __restrict__ a2,
    int* __restrict__ deg, float* __restrict__ ebuf) {
  int i = blockIdx.x * 256 + threadIdx.x;
  if (i >= N_EDGES) return;
  int s = src[i], d = dstp[i];
  float ev = a1[s] + a2[d];
  ev = ev > 0.f ? ev : 0.2f * ev;  // leaky_relu slope 0.2
  ebuf[i] = ev;
  atomicAdd(&deg[d], 1);
}

// ---------------------------------------------------------------------------
// K3a/b/c: hierarchical exclusive scan of deg[50000] -> off (and pos copy)
// 50000 = 12500 int4; 49 blocks x 256 threads x int4
// ---------------------------------------------------------------------------
#define N4 (N_NODES / 4)     // 12500
#define SCAN_NB ((N4 + 255) / 256)  // 49

__global__ __launch_bounds__(256) void k3a_scan(const int* __restrict__ deg,
                                                int* __restrict__ off,
                                                int* __restrict__ bsum) {
  __shared__ int sw[4];
  int tid = threadIdx.x, lane = tid & 63, wid = tid >> 6;
  int i4 = blockIdx.x * 256 + tid;
  int4 v = make_int4(0, 0, 0, 0);
  if (i4 < N4) v = ((const int4*)deg)[i4];
  int local = v.x + v.y + v.z + v.w;
  int incl = local;
#pragma unroll
  for (int o = 1; o < 64; o <<= 1) {
    int t = __shfl_up(incl, o, 64);
    if (lane >= o) incl += t;
  }
  if (lane == 63) sw[wid] = incl;
  __syncthreads();
  if (tid == 0) {
    int c = 0;
#pragma unroll
    for (int w = 0; w < 4; ++w) { int t = sw[w]; sw[w] = c; c += t; }
    bsum[blockIdx.x] = c;
  }
  __syncthreads();
  int excl = incl - local + sw[wid];
  int4 o;
  o.x = excl; o.y = o.x + v.x; o.z = o.y + v.y; o.w = o.z + v.z;
  if (i4 < N4) ((int4*)off)[i4] = o;
}

__global__ __launch_bounds__(64) void k3b_scan(int* __restrict__ bsum,
                                               int* __restrict__ off) {
  int lane = threadIdx.x;
  int v = (lane < SCAN_NB) ? bsum[lane] : 0;
  int incl = v;
#pragma unroll
  for (int o = 1; o < 64; o <<= 1) {
    int t = __shfl_up(incl, o, 64);
    if (lane >= o) incl += t;
  }
  if (lane < SCAN_NB) bsum[lane] = incl - v;  // exclusive
  if (lane == 63) off[N_NODES] = incl;        // total == N_EDGES
}

__global__ __launch_bounds__(256) void k3c_add(int* __restrict__ off,
                                               const int* __restrict__ bsum,
                                               int* __restrict__ pos) {
  int i4 = blockIdx.x * 256 + threadIdx.x;
  if (i4 >= N4) return;
  int add = bsum[blockIdx.x];
  int4 v = ((const int4*)off)[i4];
  v.x += add; v.y += add; v.z += add; v.w += add;
  ((int4*)off)[i4] = v;
  ((int4*)pos)[i4] = v;
}

// ---------------------------------------------------------------------------
// K4: scatter edges into dst-sorted order via atomic cursors (one 8B write)
// ---------------------------------------------------------------------------
__global__ __launch_bounds__(256) void k4_scatter(
    const int* __restrict__ src, const int* __restrict__ dstp,
    const float* __restrict__ ebuf,
    int* __restrict__ pos, int2* __restrict__ sedge) {
  int i = blockIdx.x * 256 + threadIdx.x;
  if (i >= N_EDGES) return;
  int d = dstp[i];
  int p = atomicAdd(&pos[d], 1);
  int2 v;
  v.x = src[i];
  v.y = __float_as_int(ebuf[i]);
  sedge[p] = v;
}

// ---------------------------------------------------------------------------
// K5: per-node softmax + weighted aggregation + ELU.
// 16 lanes per node (4 nodes/wave, 16 nodes/block). Each group iterates its
// node's edge list 2 edges per step -> 8 concurrent 128B row-gathers / wave.
// ---------------------------------------------------------------------------
__global__ __launch_bounds__(256) void k5_agg(
    const int* __restrict__ off, const int2* __restrict__ sedge,
    const __half* __restrict__ h, float* __restrict__ out) {
  int tid = threadIdx.x;
  int g = tid >> 4, gl = tid & 15;
  int n = blockIdx.x * 16 + g;
  if (n >= N_NODES) return;
  int b = off[n], e = off[n + 1];

  // group max (lanes stride 16 over edges; xor<16 stays in-group)
  float m = -1e30f;
  for (int j = b + gl; j < e; j += 16)
    m = fmaxf(m, __int_as_float(sedge[j].y));
#pragma unroll
  for (int o = 8; o >= 1; o >>= 1) m = fmaxf(m, __shfl_xor(m, o, 64));

  float sum = 0.f;
  float acc0 = 0.f, acc1 = 0.f, acc2 = 0.f, acc3 = 0.f;
  const __half* __restrict__ hb = h;

  int j = b;
  for (; j + 1 < e; j += 2) {
    int2 s0 = sedge[j];
    int2 s1 = sedge[j + 1];
    uint2 r0 = *(const uint2*)(hb + (size_t)s0.x * OUT_DIM + 4 * gl);
    uint2 r1 = *(const uint2*)(hb + (size_t)s1.x * OUT_DIM + 4 * gl);
    float w0 = __expf(__int_as_float(s0.y) - m);
    float w1 = __expf(__int_as_float(s1.y) - m);
    sum += w0 + w1;
    float2 f00 = __half22float2(__builtin_bit_cast(__half2, r0.x));
    float2 f01 = __half22float2(__builtin_bit_cast(__half2, r0.y));
    float2 f10 = __half22float2(__builtin_bit_cast(__half2, r1.x));
    float2 f11 = __half22float2(__builtin_bit_cast(__half2, r1.y));
    acc0 = fmaf(w0, f00.x, acc0); acc1 = fmaf(w0, f00.y, acc1);
    acc2 = fmaf(w0, f01.x, acc2); acc3 = fmaf(w0, f01.y, acc3);
    acc0 = fmaf(w1, f10.x, acc0); acc1 = fmaf(w1, f10.y, acc1);
    acc2 = fmaf(w1, f11.x, acc2); acc3 = fmaf(w1, f11.y, acc3);
  }
  if (j < e) {
    int2 s0 = sedge[j];
    uint2 r0 = *(const uint2*)(hb + (size_t)s0.x * OUT_DIM + 4 * gl);
    float w0 = __expf(__int_as_float(s0.y) - m);
    sum += w0;
    float2 f00 = __half22float2(__builtin_bit_cast(__half2, r0.x));
    float2 f01 = __half22float2(__builtin_bit_cast(__half2, r0.y));
    acc0 = fmaf(w0, f00.x, acc0); acc1 = fmaf(w0, f00.y, acc1);
    acc2 = fmaf(w0, f01.x, acc2); acc3 = fmaf(w0, f01.y, acc3);
  }

  float inv = (e > b) ? 1.f / sum : 0.f;
  acc0 *= inv; acc1 *= inv; acc2 *= inv; acc3 *= inv;
  float4 o4;
  o4.x = acc0 > 0.f ? acc0 : (__expf(acc0) - 1.f);
  o4.y = acc1 > 0.f ? acc1 : (__expf(acc1) - 1.f);
  o4.z = acc2 > 0.f ? acc2 : (__expf(acc2) - 1.f);
  o4.w = acc3 > 0.f ? acc3 : (__expf(acc3) - 1.f);
  ((float4*)(out + (size_t)n * OUT_DIM))[gl] = o4;
}

// ---------------------------------------------------------------------------
extern "C" void kernel_launch(void* const* d_in, const int* in_sizes, int n_in,
                              void* d_out, int out_size, void* d_ws, size_t ws_size,
                              hipStream_t stream) {
  const float* x   = (const float*)d_in[0];
  const int*   ei  = (const int*)d_in[1];   // [2, E]
  const float* W   = (const float*)d_in[2];
  const float* att = (const float*)d_in[3];
  float* out = (float*)d_out;

  // workspace layout (16B-aligned chunks), ~17 MB total
  char* p = (char*)d_ws;
  __half* h  = (__half*)p;  p += (size_t)N_NODES * OUT_DIM * sizeof(__half);  // 6.4 MB
  float* a1  = (float*)p;   p += (size_t)N_NODES * sizeof(float);
  float* a2  = (float*)p;   p += (size_t)N_NODES * sizeof(float);
  int*   deg = (int*)p;     p += (size_t)N_NODES * sizeof(int);
  int*   off = (int*)p;     p += (size_t)(N_NODES + 4) * sizeof(int);
  int*   pos = (int*)p;     p += (size_t)N_NODES * sizeof(int);
  float* ebuf = (float*)p;  p += (size_t)N_EDGES * sizeof(float);             // 3.2 MB
  int2*  sedge = (int2*)p;  p += (size_t)N_EDGES * sizeof(int2);              // 6.4 MB
  int*   bsum = (int*)p;    p += 64 * sizeof(int);

  const int* src  = ei;
  const int* dstp = ei + N_EDGES;

  hipMemsetAsync(deg, 0, N_NODES * sizeof(int), stream);
  k1_gemm<<<(N_NODES + 31) / 32, 256, 0, stream>>>(x, W, att, h, a1, a2);
  k2_edge<<<(N_EDGES + 255) / 256, 256, 0, stream>>>(src, dstp, a1, a2, deg, ebuf);
  k3a_scan<<<SCAN_NB, 256, 0, stream>>>(deg, off, bsum);
  k3b_scan<<<1, 64, 0, stream>>>(bsum, off);
  k3c_add<<<SCAN_NB, 256, 0, stream>>>(off, bsum, pos);
  k4_scatter<<<(N_EDGES + 255) / 256, 256, 0, stream>>>(src, dstp, ebuf, pos, sedge);
  k5_agg<<<(N_NODES + 15) / 16, 256, 0, stream>>>(off, sedge, h, out);
}

// Round 3
// 128.131 us; speedup vs baseline: 1.8411x; 1.3338x over previous
//
#include <hip/hip_runtime.h>
#include <hip/hip_bf16.h>
#include <hip/hip_fp16.h>
#include <math.h>

#define N_NODES 50000
#define N_EDGES 800000
#define IN_DIM 128
#define OUT_DIM 64

typedef __attribute__((ext_vector_type(8))) short bf16x8;
typedef __attribute__((ext_vector_type(4))) float f32x4;

static __device__ __forceinline__ ushort f2bf(float f) {
  uint u = __float_as_uint(f);
  uint r = (u + 0x7fffu + ((u >> 16) & 1u)) >> 16;  // RNE
  return (ushort)r;
}
static __device__ __forceinline__ float bf2f(ushort h) {
  return __uint_as_float(((uint)h) << 16);
}

// ---------------------------------------------------------------------------
// K1: h = x @ W via split-bf16 MFMA (x=x_hi+x_lo, W=W_hi+W_lo; 3 MFMA terms
// give ~2^-17 effective precision). h stored fp16; a1/a2 fused in epilogue.
// Block: 256 thr (4 waves), 64 rows/block. LDS 64KB: A_hi/lo [64][128],
// BT_hi/lo [64][128] (W transposed), XOR-swizzled (byte ^= (row&7)<<4).
// ---------------------------------------------------------------------------
__global__ __launch_bounds__(256) void k1_mfma(
    const float* __restrict__ x, const float* __restrict__ W,
    const float* __restrict__ att,
    __half* __restrict__ h, float* __restrict__ a1, float* __restrict__ a2) {
  __shared__ __align__(16) ushort Ah[64 * 128];
  __shared__ __align__(16) ushort Al[64 * 128];
  __shared__ __align__(16) ushort Bh[64 * 128];
  __shared__ __align__(16) ushort Bl[64 * 128];

  int tid = threadIdx.x;
  int row0 = blockIdx.x * 64;

  // stage x tile: 64x128 f32 = 2048 float4; 8 per thread
#pragma unroll
  for (int it = 0; it < 8; ++it) {
    int i4 = it * 256 + tid;       // float4 index
    int row = i4 >> 5;             // 32 float4 per row
    int kq = i4 & 31;              // float4 within row
    int grow = row0 + row;
    if (grow > N_NODES - 1) grow = N_NODES - 1;
    float4 v = ((const float4*)x)[(size_t)grow * 32 + kq];
    ushort4 hi, lo;
    hi.x = f2bf(v.x); lo.x = f2bf(v.x - bf2f(hi.x));
    hi.y = f2bf(v.y); lo.y = f2bf(v.y - bf2f(hi.y));
    hi.z = f2bf(v.z); lo.z = f2bf(v.z - bf2f(hi.z));
    hi.w = f2bf(v.w); lo.w = f2bf(v.w - bf2f(hi.w));
    int idx = (row * 128 + kq * 4) ^ ((row & 7) << 3);
    *(ushort4*)&Ah[idx] = hi;
    *(ushort4*)&Al[idx] = lo;
  }

  // stage W transposed: BT[c][k]; thread: c = tid&63, k in [kq*32, kq*32+32)
  {
    int c = tid & 63, kq = tid >> 6;
#pragma unroll
    for (int jj = 0; jj < 4; ++jj) {
      int kb = kq * 32 + jj * 8;
      uint4 ph, pl;
      uint hp[8], lp[8];
#pragma unroll
      for (int q = 0; q < 8; ++q) {
        float wv = W[(size_t)(kb + q) * OUT_DIM + c];
        ushort hh = f2bf(wv);
        hp[q] = hh;
        lp[q] = f2bf(wv - bf2f(hh));
      }
      ph.x = hp[0] | (hp[1] << 16); ph.y = hp[2] | (hp[3] << 16);
      ph.z = hp[4] | (hp[5] << 16); ph.w = hp[6] | (hp[7] << 16);
      pl.x = lp[0] | (lp[1] << 16); pl.y = lp[2] | (lp[3] << 16);
      pl.z = lp[4] | (lp[5] << 16); pl.w = lp[6] | (lp[7] << 16);
      int idx = (c * 128 + kb) ^ ((c & 7) << 3);
      *(uint4*)&Bh[idx] = ph;
      *(uint4*)&Bl[idx] = pl;
    }
  }
  __syncthreads();

  int w = tid >> 6, l = tid & 63;
  int ml = l & 15, kg = l >> 4;

  f32x4 acc[4];
#pragma unroll
  for (int nt = 0; nt < 4; ++nt) acc[nt] = (f32x4){0.f, 0.f, 0.f, 0.f};

#pragma unroll
  for (int ks = 0; ks < 4; ++ks) {
    int arow = w * 16 + ml;
    int aidx = (arow * 128 + ks * 32 + kg * 8) ^ ((arow & 7) << 3);
    bf16x8 a_h = *(const bf16x8*)&Ah[aidx];
    bf16x8 a_l = *(const bf16x8*)&Al[aidx];
#pragma unroll
    for (int nt = 0; nt < 4; ++nt) {
      int brow = nt * 16 + ml;
      int bidx = (brow * 128 + ks * 32 + kg * 8) ^ ((brow & 7) << 3);
      bf16x8 b_h = *(const bf16x8*)&Bh[bidx];
      bf16x8 b_l = *(const bf16x8*)&Bl[bidx];
      acc[nt] = __builtin_amdgcn_mfma_f32_16x16x32_bf16(a_h, b_h, acc[nt], 0, 0, 0);
      acc[nt] = __builtin_amdgcn_mfma_f32_16x16x32_bf16(a_l, b_h, acc[nt], 0, 0, 0);
      acc[nt] = __builtin_amdgcn_mfma_f32_16x16x32_bf16(a_h, b_l, acc[nt], 0, 0, 0);
    }
  }

  // epilogue: C/D layout col=lane&15, row=(lane>>4)*4+reg  [m89]
  float t1[4], t2[4];
#pragma unroll
  for (int nt = 0; nt < 4; ++nt) {
    t1[nt] = att[nt * 16 + ml];
    t2[nt] = att[OUT_DIM + nt * 16 + ml];
  }
#pragma unroll
  for (int r = 0; r < 4; ++r) {
    int drow = kg * 4 + r;
    int grow = row0 + w * 16 + drow;
    bool ok = grow < N_NODES;
    float p1 = 0.f, p2 = 0.f;
#pragma unroll
    for (int nt = 0; nt < 4; ++nt) {
      float d = acc[nt][r];
      if (ok) h[(size_t)grow * OUT_DIM + nt * 16 + ml] = __float2half(d);
      p1 = fmaf(d, t1[nt], p1);
      p2 = fmaf(d, t2[nt], p2);
    }
#pragma unroll
    for (int o = 1; o <= 8; o <<= 1) {
      p1 += __shfl_xor(p1, o, 64);
      p2 += __shfl_xor(p2, o, 64);
    }
    if (ml == 0 && ok) { a1[grow] = p1; a2[grow] = p2; }
  }
}

// ---------------------------------------------------------------------------
// K2: histogram of edge destinations
// ---------------------------------------------------------------------------
__global__ __launch_bounds__(256) void k2_hist(const int* __restrict__ dstp,
                                               int* __restrict__ deg) {
  int i = blockIdx.x * 256 + threadIdx.x;
  if (i < N_EDGES) atomicAdd(&deg[dstp[i]], 1);
}

// ---------------------------------------------------------------------------
// K3a: per-block scan of deg (int4); K3c: bsum scan (redundant/block) + add
// ---------------------------------------------------------------------------
#define N4 (N_NODES / 4)            // 12500
#define SCAN_NB ((N4 + 255) / 256)  // 49

__global__ __launch_bounds__(256) void k3a_scan(const int* __restrict__ deg,
                                                int* __restrict__ off,
                                                int* __restrict__ bsum) {
  __shared__ int sw[4];
  int tid = threadIdx.x, lane = tid & 63, wid = tid >> 6;
  int i4 = blockIdx.x * 256 + tid;
  int4 v = make_int4(0, 0, 0, 0);
  if (i4 < N4) v = ((const int4*)deg)[i4];
  int local = v.x + v.y + v.z + v.w;
  int incl = local;
#pragma unroll
  for (int o = 1; o < 64; o <<= 1) {
    int t = __shfl_up(incl, o, 64);
    if (lane >= o) incl += t;
  }
  if (lane == 63) sw[wid] = incl;
  __syncthreads();
  if (tid == 0) {
    int c = 0;
#pragma unroll
    for (int ww = 0; ww < 4; ++ww) { int t = sw[ww]; sw[ww] = c; c += t; }
    bsum[blockIdx.x] = c;
  }
  __syncthreads();
  int excl = incl - local + sw[wid];
  int4 o;
  o.x = excl; o.y = o.x + v.x; o.z = o.y + v.y; o.w = o.z + v.z;
  if (i4 < N4) ((int4*)off)[i4] = o;
}

__global__ __launch_bounds__(256) void k3c_add(int* __restrict__ off,
                                               const int* __restrict__ bsum,
                                               int* __restrict__ pos) {
  __shared__ int sb[64];
  int tid = threadIdx.x;
  if (tid < 64) {
    int v = (tid < SCAN_NB) ? bsum[tid] : 0;
    int incl = v;
#pragma unroll
    for (int o = 1; o < 64; o <<= 1) {
      int t = __shfl_up(incl, o, 64);
      if (tid >= o) incl += t;
    }
    sb[tid] = incl - v;  // exclusive block prefix
  }
  __syncthreads();
  int i4 = blockIdx.x * 256 + tid;
  if (i4 == 0) off[N_NODES] = N_EDGES;
  if (i4 >= N4) return;
  int add = sb[blockIdx.x];
  int4 v = ((const int4*)off)[i4];
  v.x += add; v.y += add; v.z += add; v.w += add;
  ((int4*)off)[i4] = v;
  ((int4*)pos)[i4] = v;
}

// ---------------------------------------------------------------------------
// K4: per-edge w = exp(leaky_relu(a1[src]+a2[dst])), scatter {src,w} into
// dst-sorted order via atomic cursors. (No max subtraction needed: logits
// are O(1) so exp cannot overflow; softmax is shift-invariant.)
// ---------------------------------------------------------------------------
__global__ __launch_bounds__(256) void k4_scatter(
    const int* __restrict__ src, const int* __restrict__ dstp,
    const float* __restrict__ a1, const float* __restrict__ a2,
    int* __restrict__ pos, int2* __restrict__ sedge) {
  int i = blockIdx.x * 256 + threadIdx.x;
  if (i >= N_EDGES) return;
  int s = src[i], d = dstp[i];
  float ev = a1[s] + a2[d];
  ev = ev > 0.f ? ev : 0.2f * ev;  // leaky_relu slope 0.2
  float wv = __expf(ev);
  int p = atomicAdd(&pos[d], 1);
  sedge[p] = make_int2(s, __float_as_int(wv));
}

// ---------------------------------------------------------------------------
// K5: per-node weighted aggregation + ELU, single pass (w precomputed).
// 16 lanes/node, 4 nodes/wave, 4-edge unroll -> 16 row-gathers in flight.
// ---------------------------------------------------------------------------
__global__ __launch_bounds__(256) void k5_agg(
    const int* __restrict__ off, const int2* __restrict__ sedge,
    const __half* __restrict__ h, float* __restrict__ out) {
  int tid = threadIdx.x;
  int g = tid >> 4, gl = tid & 15;
  int n = blockIdx.x * 16 + g;
  if (n >= N_NODES) return;
  int b = off[n], e = off[n + 1];

  float sum = 0.f;
  float acc0 = 0.f, acc1 = 0.f, acc2 = 0.f, acc3 = 0.f;
  const __half* __restrict__ hb = h;

  int j = b;
  for (; j + 3 < e; j += 4) {
    int2 s0 = sedge[j], s1 = sedge[j + 1], s2 = sedge[j + 2], s3 = sedge[j + 3];
    uint2 r0 = *(const uint2*)(hb + (size_t)s0.x * OUT_DIM + 4 * gl);
    uint2 r1 = *(const uint2*)(hb + (size_t)s1.x * OUT_DIM + 4 * gl);
    uint2 r2 = *(const uint2*)(hb + (size_t)s2.x * OUT_DIM + 4 * gl);
    uint2 r3 = *(const uint2*)(hb + (size_t)s3.x * OUT_DIM + 4 * gl);
    float w0 = __int_as_float(s0.y), w1 = __int_as_float(s1.y);
    float w2 = __int_as_float(s2.y), w3 = __int_as_float(s3.y);
    sum += (w0 + w1) + (w2 + w3);
    float2 f;
    f = __half22float2(__builtin_bit_cast(__half2, r0.x)); acc0 = fmaf(w0, f.x, acc0); acc1 = fmaf(w0, f.y, acc1);
    f = __half22float2(__builtin_bit_cast(__half2, r0.y)); acc2 = fmaf(w0, f.x, acc2); acc3 = fmaf(w0, f.y, acc3);
    f = __half22float2(__builtin_bit_cast(__half2, r1.x)); acc0 = fmaf(w1, f.x, acc0); acc1 = fmaf(w1, f.y, acc1);
    f = __half22float2(__builtin_bit_cast(__half2, r1.y)); acc2 = fmaf(w1, f.x, acc2); acc3 = fmaf(w1, f.y, acc3);
    f = __half22float2(__builtin_bit_cast(__half2, r2.x)); acc0 = fmaf(w2, f.x, acc0); acc1 = fmaf(w2, f.y, acc1);
    f = __half22float2(__builtin_bit_cast(__half2, r2.y)); acc2 = fmaf(w2, f.x, acc2); acc3 = fmaf(w2, f.y, acc3);
    f = __half22float2(__builtin_bit_cast(__half2, r3.x)); acc0 = fmaf(w3, f.x, acc0); acc1 = fmaf(w3, f.y, acc1);
    f = __half22float2(__builtin_bit_cast(__half2, r3.y)); acc2 = fmaf(w3, f.x, acc2); acc3 = fmaf(w3, f.y, acc3);
  }
  for (; j < e; ++j) {
    int2 s0 = sedge[j];
    uint2 r0 = *(const uint2*)(hb + (size_t)s0.x * OUT_DIM + 4 * gl);
    float w0 = __int_as_float(s0.y);
    sum += w0;
    float2 f;
    f = __half22float2(__builtin_bit_cast(__half2, r0.x)); acc0 = fmaf(w0, f.x, acc0); acc1 = fmaf(w0, f.y, acc1);
    f = __half22float2(__builtin_bit_cast(__half2, r0.y)); acc2 = fmaf(w0, f.x, acc2); acc3 = fmaf(w0, f.y, acc3);
  }

  float inv = (e > b) ? 1.f / sum : 0.f;
  acc0 *= inv; acc1 *= inv; acc2 *= inv; acc3 *= inv;
  float4 o4;
  o4.x = acc0 > 0.f ? acc0 : (__expf(acc0) - 1.f);
  o4.y = acc1 > 0.f ? acc1 : (__expf(acc1) - 1.f);
  o4.z = acc2 > 0.f ? acc2 : (__expf(acc2) - 1.f);
  o4.w = acc3 > 0.f ? acc3 : (__expf(acc3) - 1.f);
  ((float4*)(out + (size_t)n * OUT_DIM))[gl] = o4;
}

// ---------------------------------------------------------------------------
extern "C" void kernel_launch(void* const* d_in, const int* in_sizes, int n_in,
                              void* d_out, int out_size, void* d_ws, size_t ws_size,
                              hipStream_t stream) {
  const float* x   = (const float*)d_in[0];
  const int*   ei  = (const int*)d_in[1];   // [2, E]
  const float* W   = (const float*)d_in[2];
  const float* att = (const float*)d_in[3];
  float* out = (float*)d_out;

  char* p = (char*)d_ws;
  __half* h  = (__half*)p;  p += (size_t)N_NODES * OUT_DIM * sizeof(__half);  // 6.4 MB
  float* a1  = (float*)p;   p += (size_t)N_NODES * sizeof(float);
  float* a2  = (float*)p;   p += (size_t)N_NODES * sizeof(float);
  int*   deg = (int*)p;     p += (size_t)N_NODES * sizeof(int);
  int*   off = (int*)p;     p += (size_t)(N_NODES + 4) * sizeof(int);
  int*   pos = (int*)p;     p += (size_t)N_NODES * sizeof(int);
  int2*  sedge = (int2*)p;  p += (size_t)N_EDGES * sizeof(int2);              // 6.4 MB
  int*   bsum = (int*)p;    p += 64 * sizeof(int);

  const int* src  = ei;
  const int* dstp = ei + N_EDGES;

  hipMemsetAsync(deg, 0, N_NODES * sizeof(int), stream);
  k1_mfma<<<(N_NODES + 63) / 64, 256, 0, stream>>>(x, W, att, h, a1, a2);
  k2_hist<<<(N_EDGES + 255) / 256, 256, 0, stream>>>(dstp, deg);
  k3a_scan<<<SCAN_NB, 256, 0, stream>>>(deg, off, bsum);
  k3c_add<<<SCAN_NB, 256, 0, stream>>>(off, bsum, pos);
  k4_scatter<<<(N_EDGES + 255) / 256, 256, 0, stream>>>(src, dstp, a1, a2, pos, sedge);
  k5_agg<<<(N_NODES + 15) / 16, 256, 0, stream>>>(off, sedge, h, out);
}

// Round 4
// 97.540 us; speedup vs baseline: 2.4185x; 1.3136x over previous
//
#include <hip/hip_runtime.h>
#include <hip/hip_bf16.h>
#include <hip/hip_fp16.h>
#include <math.h>

#define N_NODES 50000
#define N_EDGES 800000
#define IN_DIM 128
#define OUT_DIM 64

typedef __attribute__((ext_vector_type(8))) short bf16x8;
typedef __attribute__((ext_vector_type(4))) float f32x4;

static __device__ __forceinline__ ushort f2bf(float f) {
  uint u = __float_as_uint(f);
  uint r = (u + 0x7fffu + ((u >> 16) & 1u)) >> 16;  // RNE
  return (ushort)r;
}
static __device__ __forceinline__ float bf2f(ushort h) {
  return __uint_as_float(((uint)h) << 16);
}

// ---------------------------------------------------------------------------
// K1: h = x @ W via split-bf16 MFMA (3 terms ~ 2^-17 precision). h stored
// fp16; a1/a2 fused in epilogue. Also zeros deg[] (kills the 42us rocclr
// fill kernel). Block: 256 thr, 64 rows. LDS XOR-swizzled per G4.
// ---------------------------------------------------------------------------
__global__ __launch_bounds__(256) void k1_mfma(
    const float* __restrict__ x, const float* __restrict__ W,
    const float* __restrict__ att,
    __half* __restrict__ h, float* __restrict__ a1, float* __restrict__ a2,
    int* __restrict__ deg) {
  __shared__ __align__(16) ushort Ah[64 * 128];
  __shared__ __align__(16) ushort Al[64 * 128];
  __shared__ __align__(16) ushort Bh[64 * 128];
  __shared__ __align__(16) ushort Bl[64 * 128];

  int tid = threadIdx.x;
  int row0 = blockIdx.x * 64;

  // zero deg slice (ordering vs k2 guaranteed by stream serialization)
  if (tid < 64) {
    int g = row0 + tid;
    if (g < N_NODES) deg[g] = 0;
  }

  // stage x tile: 64x128 f32 = 2048 float4; 8 per thread
#pragma unroll
  for (int it = 0; it < 8; ++it) {
    int i4 = it * 256 + tid;
    int row = i4 >> 5;
    int kq = i4 & 31;
    int grow = row0 + row;
    if (grow > N_NODES - 1) grow = N_NODES - 1;
    float4 v = ((const float4*)x)[(size_t)grow * 32 + kq];
    ushort4 hi, lo;
    hi.x = f2bf(v.x); lo.x = f2bf(v.x - bf2f(hi.x));
    hi.y = f2bf(v.y); lo.y = f2bf(v.y - bf2f(hi.y));
    hi.z = f2bf(v.z); lo.z = f2bf(v.z - bf2f(hi.z));
    hi.w = f2bf(v.w); lo.w = f2bf(v.w - bf2f(hi.w));
    int idx = (row * 128 + kq * 4) ^ ((row & 7) << 3);
    *(ushort4*)&Ah[idx] = hi;
    *(ushort4*)&Al[idx] = lo;
  }

  // stage W transposed: BT[c][k]
  {
    int c = tid & 63, kq = tid >> 6;
#pragma unroll
    for (int jj = 0; jj < 4; ++jj) {
      int kb = kq * 32 + jj * 8;
      uint4 ph, pl;
      uint hp[8], lp[8];
#pragma unroll
      for (int q = 0; q < 8; ++q) {
        float wv = W[(size_t)(kb + q) * OUT_DIM + c];
        ushort hh = f2bf(wv);
        hp[q] = hh;
        lp[q] = f2bf(wv - bf2f(hh));
      }
      ph.x = hp[0] | (hp[1] << 16); ph.y = hp[2] | (hp[3] << 16);
      ph.z = hp[4] | (hp[5] << 16); ph.w = hp[6] | (hp[7] << 16);
      pl.x = lp[0] | (lp[1] << 16); pl.y = lp[2] | (lp[3] << 16);
      pl.z = lp[4] | (lp[5] << 16); pl.w = lp[6] | (lp[7] << 16);
      int idx = (c * 128 + kb) ^ ((c & 7) << 3);
      *(uint4*)&Bh[idx] = ph;
      *(uint4*)&Bl[idx] = pl;
    }
  }
  __syncthreads();

  int w = tid >> 6, l = tid & 63;
  int ml = l & 15, kg = l >> 4;

  f32x4 acc[4];
#pragma unroll
  for (int nt = 0; nt < 4; ++nt) acc[nt] = (f32x4){0.f, 0.f, 0.f, 0.f};

#pragma unroll
  for (int ks = 0; ks < 4; ++ks) {
    int arow = w * 16 + ml;
    int aidx = (arow * 128 + ks * 32 + kg * 8) ^ ((arow & 7) << 3);
    bf16x8 a_h = *(const bf16x8*)&Ah[aidx];
    bf16x8 a_l = *(const bf16x8*)&Al[aidx];
#pragma unroll
    for (int nt = 0; nt < 4; ++nt) {
      int brow = nt * 16 + ml;
      int bidx = (brow * 128 + ks * 32 + kg * 8) ^ ((brow & 7) << 3);
      bf16x8 b_h = *(const bf16x8*)&Bh[bidx];
      bf16x8 b_l = *(const bf16x8*)&Bl[bidx];
      acc[nt] = __builtin_amdgcn_mfma_f32_16x16x32_bf16(a_h, b_h, acc[nt], 0, 0, 0);
      acc[nt] = __builtin_amdgcn_mfma_f32_16x16x32_bf16(a_l, b_h, acc[nt], 0, 0, 0);
      acc[nt] = __builtin_amdgcn_mfma_f32_16x16x32_bf16(a_h, b_l, acc[nt], 0, 0, 0);
    }
  }

  // epilogue: C/D layout col=lane&15, row=(lane>>4)*4+reg  [m89]
  float t1[4], t2[4];
#pragma unroll
  for (int nt = 0; nt < 4; ++nt) {
    t1[nt] = att[nt * 16 + ml];
    t2[nt] = att[OUT_DIM + nt * 16 + ml];
  }
#pragma unroll
  for (int r = 0; r < 4; ++r) {
    int drow = kg * 4 + r;
    int grow = row0 + w * 16 + drow;
    bool ok = grow < N_NODES;
    float p1 = 0.f, p2 = 0.f;
#pragma unroll
    for (int nt = 0; nt < 4; ++nt) {
      float d = acc[nt][r];
      if (ok) h[(size_t)grow * OUT_DIM + nt * 16 + ml] = __float2half(d);
      p1 = fmaf(d, t1[nt], p1);
      p2 = fmaf(d, t2[nt], p2);
    }
#pragma unroll
    for (int o = 1; o <= 8; o <<= 1) {
      p1 += __shfl_xor(p1, o, 64);
      p2 += __shfl_xor(p2, o, 64);
    }
    if (ml == 0 && ok) { a1[grow] = p1; a2[grow] = p2; }
  }
}

// ---------------------------------------------------------------------------
// K2: histogram + rank in ONE atomic: rank[i] = old count of dst.
// 8 edges/thread -> 8 independent atomics in flight.
// ---------------------------------------------------------------------------
#define K2_T (N_EDGES / 8)  // 100000 threads
__global__ __launch_bounds__(256) void k2_rank(const int* __restrict__ dstp,
                                               int* __restrict__ deg,
                                               int* __restrict__ rank) {
  int t = blockIdx.x * 256 + threadIdx.x;
  if (t >= K2_T) return;
  int4 d0 = ((const int4*)dstp)[t * 2];
  int4 d1 = ((const int4*)dstp)[t * 2 + 1];
  int4 r0, r1;
  r0.x = atomicAdd(&deg[d0.x], 1);
  r0.y = atomicAdd(&deg[d0.y], 1);
  r0.z = atomicAdd(&deg[d0.z], 1);
  r0.w = atomicAdd(&deg[d0.w], 1);
  r1.x = atomicAdd(&deg[d1.x], 1);
  r1.y = atomicAdd(&deg[d1.y], 1);
  r1.z = atomicAdd(&deg[d1.z], 1);
  r1.w = atomicAdd(&deg[d1.w], 1);
  ((int4*)rank)[t * 2] = r0;
  ((int4*)rank)[t * 2 + 1] = r1;
}

// ---------------------------------------------------------------------------
// K3a: per-block scan of deg (int4); K3c: bsum scan + add + pack {off,a2}
// ---------------------------------------------------------------------------
#define N4 (N_NODES / 4)            // 12500
#define SCAN_NB ((N4 + 255) / 256)  // 49

__global__ __launch_bounds__(256) void k3a_scan(const int* __restrict__ deg,
                                                int* __restrict__ off,
                                                int* __restrict__ bsum) {
  __shared__ int sw[4];
  int tid = threadIdx.x, lane = tid & 63, wid = tid >> 6;
  int i4 = blockIdx.x * 256 + tid;
  int4 v = make_int4(0, 0, 0, 0);
  if (i4 < N4) v = ((const int4*)deg)[i4];
  int local = v.x + v.y + v.z + v.w;
  int incl = local;
#pragma unroll
  for (int o = 1; o < 64; o <<= 1) {
    int t = __shfl_up(incl, o, 64);
    if (lane >= o) incl += t;
  }
  if (lane == 63) sw[wid] = incl;
  __syncthreads();
  if (tid == 0) {
    int c = 0;
#pragma unroll
    for (int ww = 0; ww < 4; ++ww) { int t = sw[ww]; sw[ww] = c; c += t; }
    bsum[blockIdx.x] = c;
  }
  __syncthreads();
  int excl = incl - local + sw[wid];
  int4 o;
  o.x = excl; o.y = o.x + v.x; o.z = o.y + v.y; o.w = o.z + v.z;
  if (i4 < N4) ((int4*)off)[i4] = o;
}

__global__ __launch_bounds__(256) void k3c_add(int* __restrict__ off,
                                               const int* __restrict__ bsum,
                                               const float* __restrict__ a2,
                                               int2* __restrict__ oa2) {
  __shared__ int sb[64];
  int tid = threadIdx.x;
  if (tid < 64) {
    int v = (tid < SCAN_NB) ? bsum[tid] : 0;
    int incl = v;
#pragma unroll
    for (int o = 1; o < 64; o <<= 1) {
      int t = __shfl_up(incl, o, 64);
      if (tid >= o) incl += t;
    }
    sb[tid] = incl - v;  // exclusive block prefix
  }
  __syncthreads();
  int i4 = blockIdx.x * 256 + tid;
  if (i4 == 0) off[N_NODES] = N_EDGES;
  if (i4 >= N4) return;
  int add = sb[blockIdx.x];
  int4 v = ((const int4*)off)[i4];
  v.x += add; v.y += add; v.z += add; v.w += add;
  ((int4*)off)[i4] = v;
  float4 a = ((const float4*)a2)[i4];
  int4 p0 = make_int4(v.x, __float_as_int(a.x), v.y, __float_as_int(a.y));
  int4 p1 = make_int4(v.z, __float_as_int(a.z), v.w, __float_as_int(a.w));
  ((int4*)oa2)[i4 * 2] = p0;
  ((int4*)oa2)[i4 * 2 + 1] = p1;
}

// ---------------------------------------------------------------------------
// K4: atomic-free scatter: sedge[off[d]+rank] = {src, exp(leaky(a1+a2))}.
// 4 edges/thread -> 4 independent gather->store chains.
// ---------------------------------------------------------------------------
#define K4_T (N_EDGES / 4)  // 200000 threads
__global__ __launch_bounds__(256) void k4_scatter(
    const int* __restrict__ src, const int* __restrict__ dstp,
    const int* __restrict__ rank,
    const float* __restrict__ a1, const int2* __restrict__ oa2,
    int2* __restrict__ sedge) {
  int t = blockIdx.x * 256 + threadIdx.x;
  if (t >= K4_T) return;
  int4 s = ((const int4*)src)[t];
  int4 d = ((const int4*)dstp)[t];
  int4 r = ((const int4*)rank)[t];
  float A0 = a1[s.x], A1 = a1[s.y], A2 = a1[s.z], A3 = a1[s.w];
  int2 O0 = oa2[d.x], O1 = oa2[d.y], O2 = oa2[d.z], O3 = oa2[d.w];
  float e0 = A0 + __int_as_float(O0.y);
  float e1 = A1 + __int_as_float(O1.y);
  float e2 = A2 + __int_as_float(O2.y);
  float e3 = A3 + __int_as_float(O3.y);
  e0 = e0 > 0.f ? e0 : 0.2f * e0;
  e1 = e1 > 0.f ? e1 : 0.2f * e1;
  e2 = e2 > 0.f ? e2 : 0.2f * e2;
  e3 = e3 > 0.f ? e3 : 0.2f * e3;
  // softmax is shift-invariant and logits are O(1): exp without max pass
  sedge[O0.x + r.x] = make_int2(s.x, __float_as_int(__expf(e0)));
  sedge[O1.x + r.y] = make_int2(s.y, __float_as_int(__expf(e1)));
  sedge[O2.x + r.z] = make_int2(s.z, __float_as_int(__expf(e2)));
  sedge[O3.x + r.w] = make_int2(s.w, __float_as_int(__expf(e3)));
}

// ---------------------------------------------------------------------------
// K5: per-node weighted aggregation + ELU, single pass (w precomputed).
// 16 lanes/node, 4 nodes/wave, 4-edge unroll -> 16 row-gathers in flight.
// ---------------------------------------------------------------------------
__global__ __launch_bounds__(256) void k5_agg(
    const int* __restrict__ off, const int2* __restrict__ sedge,
    const __half* __restrict__ h, float* __restrict__ out) {
  int tid = threadIdx.x;
  int g = tid >> 4, gl = tid & 15;
  int n = blockIdx.x * 16 + g;
  if (n >= N_NODES) return;
  int b = off[n], e = off[n + 1];

  float sum = 0.f;
  float acc0 = 0.f, acc1 = 0.f, acc2 = 0.f, acc3 = 0.f;
  const __half* __restrict__ hb = h;

  int j = b;
  for (; j + 3 < e; j += 4) {
    int2 s0 = sedge[j], s1 = sedge[j + 1], s2 = sedge[j + 2], s3 = sedge[j + 3];
    uint2 r0 = *(const uint2*)(hb + (size_t)s0.x * OUT_DIM + 4 * gl);
    uint2 r1 = *(const uint2*)(hb + (size_t)s1.x * OUT_DIM + 4 * gl);
    uint2 r2 = *(const uint2*)(hb + (size_t)s2.x * OUT_DIM + 4 * gl);
    uint2 r3 = *(const uint2*)(hb + (size_t)s3.x * OUT_DIM + 4 * gl);
    float w0 = __int_as_float(s0.y), w1 = __int_as_float(s1.y);
    float w2 = __int_as_float(s2.y), w3 = __int_as_float(s3.y);
    sum += (w0 + w1) + (w2 + w3);
    float2 f;
    f = __half22float2(__builtin_bit_cast(__half2, r0.x)); acc0 = fmaf(w0, f.x, acc0); acc1 = fmaf(w0, f.y, acc1);
    f = __half22float2(__builtin_bit_cast(__half2, r0.y)); acc2 = fmaf(w0, f.x, acc2); acc3 = fmaf(w0, f.y, acc3);
    f = __half22float2(__builtin_bit_cast(__half2, r1.x)); acc0 = fmaf(w1, f.x, acc0); acc1 = fmaf(w1, f.y, acc1);
    f = __half22float2(__builtin_bit_cast(__half2, r1.y)); acc2 = fmaf(w1, f.x, acc2); acc3 = fmaf(w1, f.y, acc3);
    f = __half22float2(__builtin_bit_cast(__half2, r2.x)); acc0 = fmaf(w2, f.x, acc0); acc1 = fmaf(w2, f.y, acc1);
    f = __half22float2(__builtin_bit_cast(__half2, r2.y)); acc2 = fmaf(w2, f.x, acc2); acc3 = fmaf(w2, f.y, acc3);
    f = __half22float2(__builtin_bit_cast(__half2, r3.x)); acc0 = fmaf(w3, f.x, acc0); acc1 = fmaf(w3, f.y, acc1);
    f = __half22float2(__builtin_bit_cast(__half2, r3.y)); acc2 = fmaf(w3, f.x, acc2); acc3 = fmaf(w3, f.y, acc3);
  }
  for (; j < e; ++j) {
    int2 s0 = sedge[j];
    uint2 r0 = *(const uint2*)(hb + (size_t)s0.x * OUT_DIM + 4 * gl);
    float w0 = __int_as_float(s0.y);
    sum += w0;
    float2 f;
    f = __half22float2(__builtin_bit_cast(__half2, r0.x)); acc0 = fmaf(w0, f.x, acc0); acc1 = fmaf(w0, f.y, acc1);
    f = __half22float2(__builtin_bit_cast(__half2, r0.y)); acc2 = fmaf(w0, f.x, acc2); acc3 = fmaf(w0, f.y, acc3);
  }

  float inv = (e > b) ? 1.f / sum : 0.f;
  acc0 *= inv; acc1 *= inv; acc2 *= inv; acc3 *= inv;
  float4 o4;
  o4.x = acc0 > 0.f ? acc0 : (__expf(acc0) - 1.f);
  o4.y = acc1 > 0.f ? acc1 : (__expf(acc1) - 1.f);
  o4.z = acc2 > 0.f ? acc2 : (__expf(acc2) - 1.f);
  o4.w = acc3 > 0.f ? acc3 : (__expf(acc3) - 1.f);
  ((float4*)(out + (size_t)n * OUT_DIM))[gl] = o4;
}

// ---------------------------------------------------------------------------
extern "C" void kernel_launch(void* const* d_in, const int* in_sizes, int n_in,
                              void* d_out, int out_size, void* d_ws, size_t ws_size,
                              hipStream_t stream) {
  const float* x   = (const float*)d_in[0];
  const int*   ei  = (const int*)d_in[1];   // [2, E]
  const float* W   = (const float*)d_in[2];
  const float* att = (const float*)d_in[3];
  float* out = (float*)d_out;

  char* p = (char*)d_ws;
  __half* h  = (__half*)p;  p += (size_t)N_NODES * OUT_DIM * sizeof(__half);  // 6.4 MB
  float* a1  = (float*)p;   p += (size_t)N_NODES * sizeof(float);
  float* a2  = (float*)p;   p += (size_t)N_NODES * sizeof(float);
  int*   deg = (int*)p;     p += (size_t)N_NODES * sizeof(int);
  int*   off = (int*)p;     p += (size_t)(N_NODES + 4) * sizeof(int);
  int2*  oa2 = (int2*)p;    p += (size_t)N_NODES * sizeof(int2);
  int*   rank = (int*)p;    p += (size_t)N_EDGES * sizeof(int);               // 3.2 MB
  int2*  sedge = (int2*)p;  p += (size_t)N_EDGES * sizeof(int2);              // 6.4 MB
  int*   bsum = (int*)p;    p += 64 * sizeof(int);

  const int* src  = ei;
  const int* dstp = ei + N_EDGES;

  k1_mfma<<<(N_NODES + 63) / 64, 256, 0, stream>>>(x, W, att, h, a1, a2, deg);
  k2_rank<<<(K2_T + 255) / 256, 256, 0, stream>>>(dstp, deg, rank);
  k3a_scan<<<SCAN_NB, 256, 0, stream>>>(deg, off, bsum);
  k3c_add<<<SCAN_NB, 256, 0, stream>>>(off, bsum, a2, oa2);
  k4_scatter<<<(K4_T + 255) / 256, 256, 0, stream>>>(src, dstp, rank, a1, oa2, sedge);
  k5_agg<<<(N_NODES + 15) / 16, 256, 0, stream>>>(off, sedge, h, out);
}

// Round 5
// 91.694 us; speedup vs baseline: 2.5727x; 1.0638x over previous
//
#include <hip/hip_runtime.h>
#include <hip/hip_bf16.h>
#include <hip/hip_fp16.h>
#include <math.h>

#define N_NODES 50000
#define N_EDGES 800000
#define IN_DIM 128
#define OUT_DIM 64

typedef __attribute__((ext_vector_type(8))) short bf16x8;
typedef __attribute__((ext_vector_type(4))) float f32x4;

static __device__ __forceinline__ ushort f2bf(float f) {
  uint u = __float_as_uint(f);
  uint r = (u + 0x7fffu + ((u >> 16) & 1u)) >> 16;  // RNE
  return (ushort)r;
}
static __device__ __forceinline__ float bf2f(ushort h) {
  return __uint_as_float(((uint)h) << 16);
}

#define N4 (N_NODES / 4)            // 12500
#define SCAN_NB ((N4 + 255) / 256)  // 49
#define RANK_NB ((N_EDGES / 8 + 255) / 256)   // 391 blocks, 8 edges/thread
#define GEMM_NB ((N_NODES + 63) / 64)         // 782 tiles
#define K2_T (N_EDGES / 8)                    // 100000
#define K4_T (N_EDGES / 8)                    // 100000

// ---------------------------------------------------------------------------
// K0: zero deg (tiny; replaces 42us rocclr fill / intra-kernel race)
// ---------------------------------------------------------------------------
__global__ __launch_bounds__(256) void k0_zero(int* __restrict__ deg) {
  int i4 = blockIdx.x * 256 + threadIdx.x;
  if (i4 < N4) ((int4*)deg)[i4] = make_int4(0, 0, 0, 0);
}

// ---------------------------------------------------------------------------
// K12: heterogeneous fused kernel.
//  blocks [0, RANK_NB):       rank[i] = atomicAdd(&deg[dst[i]], 1)  (8/thread)
//  blocks [RANK_NB, +GEMM_NB): h = x@W split-bf16 MFMA (2 terms:
//       x_hi*W_hi + x_lo*W_hi; W-bf16 rounding error ~6e-4 std, OK vs 1.9e-2)
//       + fused a1/a2 epilogue. LDS 48KB -> 3 blocks/CU.
// Rank blocks are latency-bound, GEMM blocks VALU/MFMA-bound: co-scheduled.
// ---------------------------------------------------------------------------
__global__ __launch_bounds__(256) void k12_fused(
    const float* __restrict__ x, const float* __restrict__ W,
    const float* __restrict__ att, const int* __restrict__ dstp,
    __half* __restrict__ h, float* __restrict__ a1, float* __restrict__ a2,
    int* __restrict__ deg, int* __restrict__ rank) {
  __shared__ __align__(16) ushort Ah[64 * 128];
  __shared__ __align__(16) ushort Al[64 * 128];
  __shared__ __align__(16) ushort Bh[64 * 128];

  int tid = threadIdx.x;

  if (blockIdx.x < RANK_NB) {
    // ---- rank/histogram role ----
    int t = blockIdx.x * 256 + tid;
    if (t >= K2_T) return;
    int4 d0 = ((const int4*)dstp)[t * 2];
    int4 d1 = ((const int4*)dstp)[t * 2 + 1];
    int4 r0, r1;
    r0.x = atomicAdd(&deg[d0.x], 1);
    r0.y = atomicAdd(&deg[d0.y], 1);
    r0.z = atomicAdd(&deg[d0.z], 1);
    r0.w = atomicAdd(&deg[d0.w], 1);
    r1.x = atomicAdd(&deg[d1.x], 1);
    r1.y = atomicAdd(&deg[d1.y], 1);
    r1.z = atomicAdd(&deg[d1.z], 1);
    r1.w = atomicAdd(&deg[d1.w], 1);
    ((int4*)rank)[t * 2] = r0;
    ((int4*)rank)[t * 2 + 1] = r1;
    return;
  }

  // ---- GEMM role ----
  int row0 = (blockIdx.x - RANK_NB) * 64;

  // stage x tile: 64x128 f32 = 2048 float4; 8 per thread; split hi/lo bf16
#pragma unroll
  for (int it = 0; it < 8; ++it) {
    int i4 = it * 256 + tid;
    int row = i4 >> 5;
    int kq = i4 & 31;
    int grow = row0 + row;
    if (grow > N_NODES - 1) grow = N_NODES - 1;
    float4 v = ((const float4*)x)[(size_t)grow * 32 + kq];
    ushort4 hi, lo;
    hi.x = f2bf(v.x); lo.x = f2bf(v.x - bf2f(hi.x));
    hi.y = f2bf(v.y); lo.y = f2bf(v.y - bf2f(hi.y));
    hi.z = f2bf(v.z); lo.z = f2bf(v.z - bf2f(hi.z));
    hi.w = f2bf(v.w); lo.w = f2bf(v.w - bf2f(hi.w));
    int idx = (row * 128 + kq * 4) ^ ((row & 7) << 3);
    *(ushort4*)&Ah[idx] = hi;
    *(ushort4*)&Al[idx] = lo;
  }

  // stage W transposed (hi only): BT[c][k]
  {
    int c = tid & 63, kq = tid >> 6;
#pragma unroll
    for (int jj = 0; jj < 4; ++jj) {
      int kb = kq * 32 + jj * 8;
      uint4 ph;
      uint hp[8];
#pragma unroll
      for (int q = 0; q < 8; ++q) hp[q] = f2bf(W[(size_t)(kb + q) * OUT_DIM + c]);
      ph.x = hp[0] | (hp[1] << 16); ph.y = hp[2] | (hp[3] << 16);
      ph.z = hp[4] | (hp[5] << 16); ph.w = hp[6] | (hp[7] << 16);
      int idx = (c * 128 + kb) ^ ((c & 7) << 3);
      *(uint4*)&Bh[idx] = ph;
    }
  }
  __syncthreads();

  int w = tid >> 6, l = tid & 63;
  int ml = l & 15, kg = l >> 4;

  f32x4 acc[4];
#pragma unroll
  for (int nt = 0; nt < 4; ++nt) acc[nt] = (f32x4){0.f, 0.f, 0.f, 0.f};

#pragma unroll
  for (int ks = 0; ks < 4; ++ks) {
    int arow = w * 16 + ml;
    int aidx = (arow * 128 + ks * 32 + kg * 8) ^ ((arow & 7) << 3);
    bf16x8 a_h = *(const bf16x8*)&Ah[aidx];
    bf16x8 a_l = *(const bf16x8*)&Al[aidx];
#pragma unroll
    for (int nt = 0; nt < 4; ++nt) {
      int brow = nt * 16 + ml;
      int bidx = (brow * 128 + ks * 32 + kg * 8) ^ ((brow & 7) << 3);
      bf16x8 b_h = *(const bf16x8*)&Bh[bidx];
      acc[nt] = __builtin_amdgcn_mfma_f32_16x16x32_bf16(a_h, b_h, acc[nt], 0, 0, 0);
      acc[nt] = __builtin_amdgcn_mfma_f32_16x16x32_bf16(a_l, b_h, acc[nt], 0, 0, 0);
    }
  }

  // epilogue: C/D layout col=lane&15, row=(lane>>4)*4+reg  [m89]
  float t1[4], t2[4];
#pragma unroll
  for (int nt = 0; nt < 4; ++nt) {
    t1[nt] = att[nt * 16 + ml];
    t2[nt] = att[OUT_DIM + nt * 16 + ml];
  }
#pragma unroll
  for (int r = 0; r < 4; ++r) {
    int drow = kg * 4 + r;
    int grow = row0 + w * 16 + drow;
    bool ok = grow < N_NODES;
    float p1 = 0.f, p2 = 0.f;
#pragma unroll
    for (int nt = 0; nt < 4; ++nt) {
      float d = acc[nt][r];
      if (ok) h[(size_t)grow * OUT_DIM + nt * 16 + ml] = __float2half(d);
      p1 = fmaf(d, t1[nt], p1);
      p2 = fmaf(d, t2[nt], p2);
    }
#pragma unroll
    for (int o = 1; o <= 8; o <<= 1) {
      p1 += __shfl_xor(p1, o, 64);
      p2 += __shfl_xor(p2, o, 64);
    }
    if (ml == 0 && ok) { a1[grow] = p1; a2[grow] = p2; }
  }
}

// ---------------------------------------------------------------------------
// K3a: per-block scan of deg (int4); K3c: bsum scan + add + pack {off,a2}
// ---------------------------------------------------------------------------
__global__ __launch_bounds__(256) void k3a_scan(const int* __restrict__ deg,
                                                int* __restrict__ off,
                                                int* __restrict__ bsum) {
  __shared__ int sw[4];
  int tid = threadIdx.x, lane = tid & 63, wid = tid >> 6;
  int i4 = blockIdx.x * 256 + tid;
  int4 v = make_int4(0, 0, 0, 0);
  if (i4 < N4) v = ((const int4*)deg)[i4];
  int local = v.x + v.y + v.z + v.w;
  int incl = local;
#pragma unroll
  for (int o = 1; o < 64; o <<= 1) {
    int t = __shfl_up(incl, o, 64);
    if (lane >= o) incl += t;
  }
  if (lane == 63) sw[wid] = incl;
  __syncthreads();
  if (tid == 0) {
    int c = 0;
#pragma unroll
    for (int ww = 0; ww < 4; ++ww) { int t = sw[ww]; sw[ww] = c; c += t; }
    bsum[blockIdx.x] = c;
  }
  __syncthreads();
  int excl = incl - local + sw[wid];
  int4 o;
  o.x = excl; o.y = o.x + v.x; o.z = o.y + v.y; o.w = o.z + v.z;
  if (i4 < N4) ((int4*)off)[i4] = o;
}

__global__ __launch_bounds__(256) void k3c_add(int* __restrict__ off,
                                               const int* __restrict__ bsum,
                                               const float* __restrict__ a2,
                                               int2* __restrict__ oa2) {
  __shared__ int sb[64];
  int tid = threadIdx.x;
  if (tid < 64) {
    int v = (tid < SCAN_NB) ? bsum[tid] : 0;
    int incl = v;
#pragma unroll
    for (int o = 1; o < 64; o <<= 1) {
      int t = __shfl_up(incl, o, 64);
      if (tid >= o) incl += t;
    }
    sb[tid] = incl - v;  // exclusive block prefix
  }
  __syncthreads();
  int i4 = blockIdx.x * 256 + tid;
  if (i4 == 0) off[N_NODES] = N_EDGES;
  if (i4 >= N4) return;
  int add = sb[blockIdx.x];
  int4 v = ((const int4*)off)[i4];
  v.x += add; v.y += add; v.z += add; v.w += add;
  ((int4*)off)[i4] = v;
  float4 a = ((const float4*)a2)[i4];
  int4 p0 = make_int4(v.x, __float_as_int(a.x), v.y, __float_as_int(a.y));
  int4 p1 = make_int4(v.z, __float_as_int(a.z), v.w, __float_as_int(a.w));
  ((int4*)oa2)[i4 * 2] = p0;
  ((int4*)oa2)[i4 * 2 + 1] = p1;
}

// ---------------------------------------------------------------------------
// K4: atomic-free scatter, 8 edges/thread (8 independent gather->store chains)
// sedge[off[d]+rank] = {src, exp(leaky(a1+a2))}
// ---------------------------------------------------------------------------
__global__ __launch_bounds__(256) void k4_scatter(
    const int* __restrict__ src, const int* __restrict__ dstp,
    const int* __restrict__ rank,
    const float* __restrict__ a1, const int2* __restrict__ oa2,
    int2* __restrict__ sedge) {
  int t = blockIdx.x * 256 + threadIdx.x;
  if (t >= K4_T) return;
  int4 s0 = ((const int4*)src)[t * 2],  s1 = ((const int4*)src)[t * 2 + 1];
  int4 d0 = ((const int4*)dstp)[t * 2], d1 = ((const int4*)dstp)[t * 2 + 1];
  int4 r0 = ((const int4*)rank)[t * 2], r1 = ((const int4*)rank)[t * 2 + 1];
  float A[8];
  A[0] = a1[s0.x]; A[1] = a1[s0.y]; A[2] = a1[s0.z]; A[3] = a1[s0.w];
  A[4] = a1[s1.x]; A[5] = a1[s1.y]; A[6] = a1[s1.z]; A[7] = a1[s1.w];
  int2 O[8];
  O[0] = oa2[d0.x]; O[1] = oa2[d0.y]; O[2] = oa2[d0.z]; O[3] = oa2[d0.w];
  O[4] = oa2[d1.x]; O[5] = oa2[d1.y]; O[6] = oa2[d1.z]; O[7] = oa2[d1.w];
  int S[8] = {s0.x, s0.y, s0.z, s0.w, s1.x, s1.y, s1.z, s1.w};
  int R[8] = {r0.x, r0.y, r0.z, r0.w, r1.x, r1.y, r1.z, r1.w};
#pragma unroll
  for (int q = 0; q < 8; ++q) {
    float e = A[q] + __int_as_float(O[q].y);
    e = e > 0.f ? e : 0.2f * e;  // leaky_relu 0.2
    // logits O(1): exp w/o max pass (softmax shift-invariant)
    sedge[O[q].x + R[q]] = make_int2(S[q], __float_as_int(__expf(e)));
  }
}

// ---------------------------------------------------------------------------
// K5: per-node weighted aggregation + ELU. 8 lanes/node (uint4/lane),
// 8 nodes/wave, 4-edge unroll -> 32 row-gathers in flight per wave.
// ---------------------------------------------------------------------------
__global__ __launch_bounds__(256) void k5_agg(
    const int* __restrict__ off, const int2* __restrict__ sedge,
    const __half* __restrict__ h, float* __restrict__ out) {
  int tid = threadIdx.x;
  int g = tid >> 3, gl = tid & 7;
  int n = blockIdx.x * 32 + g;
  if (n >= N_NODES) return;
  int b = off[n], e = off[n + 1];

  float sum = 0.f;
  float a0 = 0.f, a1_ = 0.f, a2_ = 0.f, a3 = 0.f;
  float a4 = 0.f, a5 = 0.f, a6 = 0.f, a7 = 0.f;
  const __half* __restrict__ hb = h;

#define K5_ACC(rr, ww)                                                        \
  {                                                                           \
    float2 f;                                                                 \
    f = __half22float2(__builtin_bit_cast(__half2, rr.x));                    \
    a0 = fmaf(ww, f.x, a0); a1_ = fmaf(ww, f.y, a1_);                         \
    f = __half22float2(__builtin_bit_cast(__half2, rr.y));                    \
    a2_ = fmaf(ww, f.x, a2_); a3 = fmaf(ww, f.y, a3);                         \
    f = __half22float2(__builtin_bit_cast(__half2, rr.z));                    \
    a4 = fmaf(ww, f.x, a4); a5 = fmaf(ww, f.y, a5);                           \
    f = __half22float2(__builtin_bit_cast(__half2, rr.w));                    \
    a6 = fmaf(ww, f.x, a6); a7 = fmaf(ww, f.y, a7);                           \
  }

  int j = b;
  for (; j + 3 < e; j += 4) {
    int2 s0 = sedge[j], s1 = sedge[j + 1], s2 = sedge[j + 2], s3 = sedge[j + 3];
    uint4 r0 = ((const uint4*)(hb + (size_t)s0.x * OUT_DIM))[gl];
    uint4 r1 = ((const uint4*)(hb + (size_t)s1.x * OUT_DIM))[gl];
    uint4 r2 = ((const uint4*)(hb + (size_t)s2.x * OUT_DIM))[gl];
    uint4 r3 = ((const uint4*)(hb + (size_t)s3.x * OUT_DIM))[gl];
    float w0 = __int_as_float(s0.y), w1 = __int_as_float(s1.y);
    float w2 = __int_as_float(s2.y), w3 = __int_as_float(s3.y);
    sum += (w0 + w1) + (w2 + w3);
    K5_ACC(r0, w0); K5_ACC(r1, w1); K5_ACC(r2, w2); K5_ACC(r3, w3);
  }
  for (; j < e; ++j) {
    int2 s0 = sedge[j];
    uint4 r0 = ((const uint4*)(hb + (size_t)s0.x * OUT_DIM))[gl];
    float w0 = __int_as_float(s0.y);
    sum += w0;
    K5_ACC(r0, w0);
  }

  float inv = (e > b) ? 1.f / sum : 0.f;
  a0 *= inv; a1_ *= inv; a2_ *= inv; a3 *= inv;
  a4 *= inv; a5 *= inv; a6 *= inv; a7 *= inv;
  float4 o0, o1;
  o0.x = a0 > 0.f ? a0 : (__expf(a0) - 1.f);
  o0.y = a1_ > 0.f ? a1_ : (__expf(a1_) - 1.f);
  o0.z = a2_ > 0.f ? a2_ : (__expf(a2_) - 1.f);
  o0.w = a3 > 0.f ? a3 : (__expf(a3) - 1.f);
  o1.x = a4 > 0.f ? a4 : (__expf(a4) - 1.f);
  o1.y = a5 > 0.f ? a5 : (__expf(a5) - 1.f);
  o1.z = a6 > 0.f ? a6 : (__expf(a6) - 1.f);
  o1.w = a7 > 0.f ? a7 : (__expf(a7) - 1.f);
  float4* ob = (float4*)(out + (size_t)n * OUT_DIM);
  ob[gl * 2] = o0;
  ob[gl * 2 + 1] = o1;
}

// ---------------------------------------------------------------------------
extern "C" void kernel_launch(void* const* d_in, const int* in_sizes, int n_in,
                              void* d_out, int out_size, void* d_ws, size_t ws_size,
                              hipStream_t stream) {
  const float* x   = (const float*)d_in[0];
  const int*   ei  = (const int*)d_in[1];   // [2, E]
  const float* W   = (const float*)d_in[2];
  const float* att = (const float*)d_in[3];
  float* out = (float*)d_out;

  char* p = (char*)d_ws;
  __half* h  = (__half*)p;  p += (size_t)N_NODES * OUT_DIM * sizeof(__half);  // 6.4 MB
  float* a1  = (float*)p;   p += (size_t)N_NODES * sizeof(float);
  float* a2  = (float*)p;   p += (size_t)N_NODES * sizeof(float);
  int*   deg = (int*)p;     p += (size_t)N_NODES * sizeof(int);
  int*   off = (int*)p;     p += (size_t)(N_NODES + 4) * sizeof(int);
  int2*  oa2 = (int2*)p;    p += (size_t)N_NODES * sizeof(int2);
  int*   rank = (int*)p;    p += (size_t)N_EDGES * sizeof(int);               // 3.2 MB
  int2*  sedge = (int2*)p;  p += (size_t)N_EDGES * sizeof(int2);              // 6.4 MB
  int*   bsum = (int*)p;    p += 64 * sizeof(int);

  const int* src  = ei;
  const int* dstp = ei + N_EDGES;

  k0_zero<<<SCAN_NB, 256, 0, stream>>>(deg);
  k12_fused<<<RANK_NB + GEMM_NB, 256, 0, stream>>>(x, W, att, dstp, h, a1, a2, deg, rank);
  k3a_scan<<<SCAN_NB, 256, 0, stream>>>(deg, off, bsum);
  k3c_add<<<SCAN_NB, 256, 0, stream>>>(off, bsum, a2, oa2);
  k4_scatter<<<(K4_T + 255) / 256, 256, 0, stream>>>(src, dstp, rank, a1, oa2, sedge);
  k5_agg<<<(N_NODES + 31) / 32, 256, 0, stream>>>(off, sedge, h, out);
}